// Round 4
// baseline (326.478 us; speedup 1.0000x reference)
//
#include <hip/hip_runtime.h>

// out = FWHT(in1 * in2) / sqrt(4096), rows of length N=4096, fp32.
// R4: one WAVE per row, 64 floats/thread => 6 of the 12 index bits live in
// registers per phase => ONE LDS exchange total, no multi-wave barriers.
//   Element e (12 bits) = b(2 intra-float4 bits) | q(10 quad bits)<<2.
//   Phase 1: lane = q0..q5, regs hold (b0,b1,q6..q9) -> in-register fwht64
//            butterflies bits {0,1,8,9,10,11}. Loads: lane-contiguous float4.
//   Exchange: LDS float-index A(e) = e ^ ((q6q7q8)<<2)  (XOR swizzle, keeps
//            16B blocks intact). Writes: 16x ds_write_b128, conflict-free
//            (each instr covers a contiguous 1KB window). Reads: 64x
//            ds_read_b32, 2-way bank aliasing only (free on wave64).
//   Phase 2: lane = (b0,b1,q6..q9), regs hold q0..q5 -> fwht64 finishes
//            bits {2..7}. Stores: per-lane 64B segments via 16B pieces,
//            full lines covered across the unroll; nt (R2 win kept).
// R3 nt-loads reverted (neutral: gfx950 nt loads don't steer L3).

#define ROW_N 4096
#define NTHREADS 64

typedef float v4f __attribute__((ext_vector_type(4)));

__device__ __forceinline__ void fwht64(float x[64]) {
#pragma unroll
    for (int m = 1; m < 64; m <<= 1) {
#pragma unroll
        for (int r = 0; r < 64; ++r) {
            if ((r & m) == 0) {
                const float u = x[r];
                const float v = x[r | m];
                x[r]     = u + v;
                x[r | m] = u - v;
            }
        }
    }
}

__launch_bounds__(NTHREADS)
__global__ void fwht_mul_kernel(const float* __restrict__ a,
                                const float* __restrict__ b,
                                float* __restrict__ out) {
    __shared__ float lds[ROW_N];  // 16 KiB -> 10 blocks(waves)/CU

    const int L = threadIdx.x;            // lane 0..63
    const long long row = blockIdx.x;
    const float* __restrict__ pa = a + row * ROW_N;
    const float* __restrict__ pb = b + row * ROW_N;
    float* __restrict__ po = out + row * ROW_N;

    float x[64];

    // ---- Phase 1 load: x[b | R<<2] = element (b | (L | R<<6)<<2) ----
#pragma unroll
    for (int R = 0; R < 16; ++R) {
        const int off = (R << 8) + (L << 2);
        const v4f va = *reinterpret_cast<const v4f*>(pa + off);
        const v4f vb = *reinterpret_cast<const v4f*>(pb + off);
#pragma unroll
        for (int j = 0; j < 4; ++j) x[(R << 2) + j] = va[j] * vb[j];
    }
    fwht64(x);  // butterflies bits {b0,b1,q6,q7,q8,q9}

    // ---- Exchange: A(e) = e ^ ((q6q7q8)<<2) ----
#pragma unroll
    for (int R = 0; R < 16; ++R) {
        const int addr = ((L ^ (R & 7)) << 2) | (R << 8);
        v4f t;
#pragma unroll
        for (int j = 0; j < 4; ++j) t[j] = x[(R << 2) + j];
        *reinterpret_cast<v4f*>(&lds[addr]) = t;  // ds_write_b128
    }
    __syncthreads();  // single-wave block: ~free (waitcnt + barrier)

    const int h = L >> 2;                  // q6..q9
    const int base2 = (L & 3) | (h << 8);  // b | h<<8 (bits 2..7 are zero)
    const int m = h & 7;                   // swizzle key
#pragma unroll
    for (int r = 0; r < 64; ++r) {
        x[r] = lds[base2 + ((r ^ m) << 2)];  // element b | (r | h<<6)<<2
    }
    fwht64(x);  // butterflies bits {q0..q5}

    // ---- Store: e = base2 + r*4, scale 1/64, non-temporal ----
#pragma unroll
    for (int r = 0; r < 64; ++r) {
        __builtin_nontemporal_store(x[r] * 0.015625f, po + base2 + (r << 2));
    }
}

extern "C" void kernel_launch(void* const* d_in, const int* in_sizes, int n_in,
                              void* d_out, int out_size, void* d_ws, size_t ws_size,
                              hipStream_t stream) {
    const float* a = (const float*)d_in[0];
    const float* b = (const float*)d_in[1];
    float* out = (float*)d_out;
    const int rows = in_sizes[0] / ROW_N;  // 8192
    hipLaunchKernelGGL(fwht_mul_kernel, dim3(rows), dim3(NTHREADS), 0, stream,
                       a, b, out);
}

// Round 5
// 63.025 us; speedup vs baseline: 5.1801x; 5.1801x over previous
//
#include <hip/hip_runtime.h>

// out = FWHT(in1 * in2) / sqrt(4096), rows of length N=4096, fp32.
// One row per 256-thread block; 16 elements/thread in registers.
// 12 index bits partitioned into 3 register-held groups of 4; 16-pt
// in-register FWHT per phase, LDS exchange between phases (pad l+(l>>5):
// <=2-way bank aliasing, free on wave64/32-bank).
// R2: non-temporal output stores (write-allocate pollution fix, 77->63us).
// R3: nt LOADS neutral (gfx950 nt loads don't steer L3 allocation) - reverted.
// R4: 1-wave/row single-exchange variant REGRESSED 5x: scattered per-lane
//     stores caused 2.8x HBM write amplification + 22% occupancy. Reverted.
//     Lesson: stores must stay lane-contiguous.
// Roofline: CU-side traffic is the algorithmic minimum 402.7 MB; at 63 us
// that is 6.39 TB/s = ~101% of the measured copy ceiling (6.29 TB/s, m13).
// L3 is memory-side (hits still cross the CU<->memory fabric), so this is
// the binding limit.

#define ROW_N 4096
#define NTHREADS 256

__device__ __forceinline__ int lpad(int l) { return l + (l >> 5); }

__device__ __forceinline__ void fwht16(float x[16]) {
#pragma unroll
    for (int m = 1; m < 16; m <<= 1) {
#pragma unroll
        for (int r = 0; r < 16; ++r) {
            if ((r & m) == 0) {
                const float u = x[r];
                const float v = x[r | m];
                x[r]     = u + v;
                x[r | m] = u - v;
            }
        }
    }
}

__launch_bounds__(NTHREADS)
__global__ void fwht_mul_kernel(const float* __restrict__ a,
                                const float* __restrict__ b,
                                float* __restrict__ out) {
    __shared__ float lds[ROW_N + (ROW_N >> 5)];  // 4224 floats = 16.9 KiB

    const int t = threadIdx.x;
    const long long row = blockIdx.x;
    const float* __restrict__ pa = a + row * ROW_N;
    const float* __restrict__ pb = b + row * ROW_N;
    float* __restrict__ po = out + row * ROW_N;

    float x[16];

    // ---- Phase 1: regs hold element bits {0,1,10,11} ----
#pragma unroll
    for (int r4 = 0; r4 < 4; ++r4) {
        const int off = (r4 << 10) + (t << 2);
        const float4 va = *reinterpret_cast<const float4*>(pa + off);
        const float4 vb = *reinterpret_cast<const float4*>(pb + off);
        x[r4 * 4 + 0] = va.x * vb.x;
        x[r4 * 4 + 1] = va.y * vb.y;
        x[r4 * 4 + 2] = va.z * vb.z;
        x[r4 * 4 + 3] = va.w * vb.w;
    }
    fwht16(x);  // butterflies over bits 0,1,10,11

    // ---- Exchange 1: to regs = bits {2..5} ----
#pragma unroll
    for (int r = 0; r < 16; ++r) {
        const int l = (r & 3) | (t << 2) | ((r >> 2) << 10);
        lds[lpad(l)] = x[r];
    }
    __syncthreads();
#pragma unroll
    for (int r = 0; r < 16; ++r) {
        const int l = (t & 3) | (r << 2) | ((t >> 2) << 6);
        x[r] = lds[lpad(l)];
    }
    fwht16(x);  // butterflies over bits 2..5

    // ---- Exchange 2: to regs = bits {6..9} ----
    __syncthreads();
#pragma unroll
    for (int r = 0; r < 16; ++r) {
        const int l = (t & 3) | (r << 2) | ((t >> 2) << 6);
        lds[lpad(l)] = x[r];
    }
    __syncthreads();
#pragma unroll
    for (int r = 0; r < 16; ++r) {
        const int l = (t & 63) | (r << 6) | ((t >> 6) << 10);
        x[r] = lds[lpad(l)];
    }
    fwht16(x);  // butterflies over bits 6..9

    // ---- Store (scale = 1/64), non-temporal, lane-contiguous ----
#pragma unroll
    for (int r = 0; r < 16; ++r) {
        const int l = (t & 63) | (r << 6) | ((t >> 6) << 10);
        __builtin_nontemporal_store(x[r] * 0.015625f, po + l);
    }
}

extern "C" void kernel_launch(void* const* d_in, const int* in_sizes, int n_in,
                              void* d_out, int out_size, void* d_ws, size_t ws_size,
                              hipStream_t stream) {
    const float* a = (const float*)d_in[0];
    const float* b = (const float*)d_in[1];
    float* out = (float*)d_out;
    const int rows = in_sizes[0] / ROW_N;  // 8192
    hipLaunchKernelGGL(fwht_mul_kernel, dim3(rows), dim3(NTHREADS), 0, stream,
                       a, b, out);
}